// Round 5
// baseline (1648.478 us; speedup 1.0000x reference)
//
#include <hip/hip_runtime.h>
#include <math.h>

// LearnableVisitEncoder — 2-kernel pipeline, all fp32:
//   A vocab_fused : emb[20000,128] -> H2 = silu(silu(emb@W1+b1)@W2+b2) (stored)
//                   L[r] = tanh(H2@Wa1+ba1) . wa2 + ba2                (stored)
//   B pool_rho    : per visit masked softmax over L[ids],
//                   h_pool = sum a_c H2[id_c]  (LDS),
//                   out = silu(h_pool@Wr1+br1)@Wr2 + br2
//
// GEMM: wave-column-split, MT=16 rows/block (vocab 1250 blocks = 4.9/CU,
// visits 1024 = 4.0/CU). Inner k-loop is FULLY unrolled with static
// indices only — round 4's runtime-indexed ping-pong arrays were demoted
// to scratch (2.6 GB of HBM spill traffic, 683 us). Compiler pipelines
// the loads itself under the __launch_bounds__(256,4) VGPR cap.

#define DIM 128
#define MT 16
#define LDP 132   // LDS row stride (528 B), 16B-aligned

__device__ __forceinline__ float silu_f(float v) {
  return v / (1.0f + expf(-v));
}

// stage 16 x 128 fp32 rows (contiguous global) into LDS tile
__device__ __forceinline__ void stage16(const float* __restrict__ src,
                                        float (*dst)[LDP], int tid) {
  const float4* s = (const float4*)src;
#pragma unroll
  for (int t = 0; t < 2; ++t) {
    int idx = tid + t * 256;          // 0..511 float4s = 16 rows x 32
    int r = idx >> 5, c4 = idx & 31;
    *(float4*)&dst[r][c4 * 4] = s[idx];
  }
}

#define FMA2(xs0, xs1, wv)                                                  \
  acc[0][0] = fmaf(xs0, wv.x, acc[0][0]);                                   \
  acc[0][1] = fmaf(xs0, wv.y, acc[0][1]);                                   \
  acc[0][2] = fmaf(xs0, wv.z, acc[0][2]);                                   \
  acc[0][3] = fmaf(xs0, wv.w, acc[0][3]);                                   \
  acc[1][0] = fmaf(xs1, wv.x, acc[1][0]);                                   \
  acc[1][1] = fmaf(xs1, wv.y, acc[1][1]);                                   \
  acc[1][2] = fmaf(xs1, wv.z, acc[1][2]);                                   \
  acc[1][3] = fmaf(xs1, wv.w, acc[1][3]);

// acc[2][4] = sIn[r0..r0+1][:] @ W[:][4*cg..4*cg+3]
// straight full unroll, static indices only (NO runtime-indexed locals)
__device__ __forceinline__ void gemm_wave16(const float (*sIn)[LDP],
                                            const float* __restrict__ Wg,
                                            int cg, int r0, float acc[2][4]) {
#pragma unroll
  for (int i = 0; i < 2; ++i)
#pragma unroll
    for (int j = 0; j < 4; ++j) acc[i][j] = 0.f;
  const float4* Wv = (const float4*)Wg;  // W[k][c]: float4 index k*32 + cg
#pragma unroll
  for (int k0 = 0; k0 < DIM; k0 += 4) {
    float4 x0 = *(const float4*)&sIn[r0 + 0][k0];
    float4 x1 = *(const float4*)&sIn[r0 + 1][k0];
    float4 w0 = Wv[(k0 + 0) * 32 + cg];
    float4 w1 = Wv[(k0 + 1) * 32 + cg];
    float4 w2 = Wv[(k0 + 2) * 32 + cg];
    float4 w3 = Wv[(k0 + 3) * 32 + cg];
    FMA2(x0.x, x1.x, w0)
    FMA2(x0.y, x1.y, w1)
    FMA2(x0.z, x1.z, w2)
    FMA2(x0.w, x1.w, w3)
  }
}

// ---------------- Kernel A: vocab side, fully fused ----------------
__global__ __launch_bounds__(256, 4) void vocab_fused(
    const float* __restrict__ emb, const float* __restrict__ W1,
    const float* __restrict__ b1, const float* __restrict__ W2,
    const float* __restrict__ b2, const float* __restrict__ Wa1,
    const float* __restrict__ ba1, const float* __restrict__ wa2,
    const float* __restrict__ ba2, float* __restrict__ H2,
    float* __restrict__ L) {
  __shared__ float sA[MT][LDP], sB[MT][LDP];
  __shared__ float sP[4][MT];
  const int tid = threadIdx.x;
  const int wid = tid >> 6, lane = tid & 63;
  const int cg = wid * 8 + (lane & 7);  // float4-col index 0..31
  const int c0 = cg * 4;
  const int r0 = (lane >> 3) * 2;       // 8 row-groups x 2 rows
  const int m0 = blockIdx.x * MT;

  stage16(emb + (size_t)m0 * DIM, sA, tid);
  __syncthreads();

  float acc[2][4];
  // layer 1: silu(emb@W1+b1) -> sB (this wave's 32-col slice)
  gemm_wave16(sA, W1, cg, r0, acc);
  {
    float4 bv = ((const float4*)b1)[cg];
#pragma unroll
    for (int i = 0; i < 2; ++i) {
      float4 o;
      o.x = silu_f(acc[i][0] + bv.x);
      o.y = silu_f(acc[i][1] + bv.y);
      o.z = silu_f(acc[i][2] + bv.z);
      o.w = silu_f(acc[i][3] + bv.w);
      *(float4*)&sB[r0 + i][c0] = o;
    }
  }
  __syncthreads();
  // layer 2: silu(sB@W2+b2) -> sA + global H2
  gemm_wave16(sB, W2, cg, r0, acc);
  {
    float4 bv = ((const float4*)b2)[cg];
#pragma unroll
    for (int i = 0; i < 2; ++i) {
      float4 o;
      o.x = silu_f(acc[i][0] + bv.x);
      o.y = silu_f(acc[i][1] + bv.y);
      o.z = silu_f(acc[i][2] + bv.z);
      o.w = silu_f(acc[i][3] + bv.w);
      *(float4*)&sA[r0 + i][c0] = o;
      *(float4*)&H2[(size_t)(m0 + r0 + i) * DIM + c0] = o;
    }
  }
  __syncthreads();
  // layer 3: tanh(sA@Wa1+ba1) . wa2 + ba2 -> L (rowdot fused)
  gemm_wave16(sA, Wa1, cg, r0, acc);
  {
    float4 bv = ((const float4*)ba1)[cg];
    float4 wv = ((const float4*)wa2)[cg];
#pragma unroll
    for (int i = 0; i < 2; ++i) {
      float g0 = tanhf(acc[i][0] + bv.x);
      float g1 = tanhf(acc[i][1] + bv.y);
      float g2 = tanhf(acc[i][2] + bv.z);
      float g3 = tanhf(acc[i][3] + bv.w);
      float p = fmaf(g0, wv.x, fmaf(g1, wv.y, fmaf(g2, wv.z, g3 * wv.w)));
#pragma unroll
      for (int m = 1; m <= 4; m <<= 1) p += __shfl_xor(p, m, 64);  // 8 cgs
      if ((lane & 7) == 0) sP[wid][r0 + i] = p;
    }
  }
  __syncthreads();
  if (tid < MT)
    L[m0 + tid] = sP[0][tid] + sP[1][tid] + sP[2][tid] + sP[3][tid] + ba2[0];
}

// ---------------- Kernel B: pool + rho fused ----------------
// Phase 1: each wave pools 4 visits (masked softmax + gathered weighted sum)
// into LDS rows. Phase 2: 2-layer rho GEMM on the 16-visit LDS tile.
__global__ __launch_bounds__(256, 4) void pool_rho(
    const int* __restrict__ ids, const float* __restrict__ L,
    const float* __restrict__ H2, const float* __restrict__ Wr1,
    const float* __restrict__ br1, const float* __restrict__ Wr2,
    const float* __restrict__ br2, float* __restrict__ out) {
  __shared__ float sA[MT][LDP], sB[MT][LDP];
  const int tid = threadIdx.x;
  const int wid = tid >> 6, lane = tid & 63;
  const int m0 = blockIdx.x * MT;
  const int half = lane >> 5, li = lane & 31;

#pragma unroll
  for (int t = 0; t < 4; ++t) {
    const int vloc = wid * 4 + t;
    const int v = m0 + vloc;
    int id = 0;
    float lg = -3.4e38f;
    if (lane < 48) {
      id = ids[(size_t)v * 48 + lane];
      if (id != 0) lg = L[id];   // PAD_IDX==0 masked
    }
    float mx = lg;
#pragma unroll
    for (int m = 32; m; m >>= 1) mx = fmaxf(mx, __shfl_xor(mx, m, 64));
    float e = (lg > -3.0e38f) ? expf(lg - mx) : 0.f;
    float s = e;
#pragma unroll
    for (int m = 32; m; m >>= 1) s += __shfl_xor(s, m, 64);
    const float a = e / s;          // pads: exactly 0

    float4 acc = make_float4(0.f, 0.f, 0.f, 0.f);
#pragma unroll 8
    for (int c = 0; c < 24; ++c) {  // lanes 0-31: even codes, 32-63: odd
      const int cc = 2 * c + half;
      const float ac = __shfl(a, cc, 64);
      const int idc = __shfl(id, cc, 64);
      const float4 h = ((const float4*)(H2 + (size_t)idc * DIM))[li];
      acc.x = fmaf(ac, h.x, acc.x); // pad: ac==0 exactly -> no-op
      acc.y = fmaf(ac, h.y, acc.y);
      acc.z = fmaf(ac, h.z, acc.z);
      acc.w = fmaf(ac, h.w, acc.w);
    }
    acc.x += __shfl_xor(acc.x, 32, 64);
    acc.y += __shfl_xor(acc.y, 32, 64);
    acc.z += __shfl_xor(acc.z, 32, 64);
    acc.w += __shfl_xor(acc.w, 32, 64);
    if (half == 0) *(float4*)&sA[vloc][li * 4] = acc;
  }
  __syncthreads();

  // rho: out = silu(sA@Wr1+br1)@Wr2 + br2
  const int cg = wid * 8 + (lane & 7);
  const int c0 = cg * 4;
  const int r0 = (lane >> 3) * 2;
  float acc[2][4];
  gemm_wave16(sA, Wr1, cg, r0, acc);
  {
    float4 bv = ((const float4*)br1)[cg];
#pragma unroll
    for (int i = 0; i < 2; ++i) {
      float4 o;
      o.x = silu_f(acc[i][0] + bv.x);
      o.y = silu_f(acc[i][1] + bv.y);
      o.z = silu_f(acc[i][2] + bv.z);
      o.w = silu_f(acc[i][3] + bv.w);
      *(float4*)&sB[r0 + i][c0] = o;
    }
  }
  __syncthreads();
  gemm_wave16(sB, Wr2, cg, r0, acc);
  {
    float4 bv = ((const float4*)br2)[cg];
#pragma unroll
    for (int i = 0; i < 2; ++i) {
      float4 o;
      o.x = acc[i][0] + bv.x;
      o.y = acc[i][1] + bv.y;
      o.z = acc[i][2] + bv.z;
      o.w = acc[i][3] + bv.w;
      *(float4*)&out[(size_t)(m0 + r0 + i) * DIM + c0] = o;
    }
  }
}

extern "C" void kernel_launch(void* const* d_in, const int* in_sizes, int n_in,
                              void* d_out, int out_size, void* d_ws,
                              size_t ws_size, hipStream_t stream) {
  const int*   ids = (const int*)  d_in[0];
  const float* emb = (const float*)d_in[1];
  const float* W1  = (const float*)d_in[2];
  const float* b1  = (const float*)d_in[3];
  const float* W2  = (const float*)d_in[4];
  const float* b2  = (const float*)d_in[5];
  const float* Wa1 = (const float*)d_in[6];
  const float* ba1 = (const float*)d_in[7];
  const float* wa2 = (const float*)d_in[8];
  const float* ba2 = (const float*)d_in[9];
  const float* Wr1 = (const float*)d_in[10];
  const float* br1 = (const float*)d_in[11];
  const float* Wr2 = (const float*)d_in[12];
  const float* br2 = (const float*)d_in[13];
  float* out = (float*)d_out;

  const int VOCAB = 20000, V = 16384;

  float* H2 = (float*)d_ws;                       // 20000*128
  float* L  = H2 + (size_t)VOCAB * DIM;           // 20000

  vocab_fused<<<VOCAB / MT, 256, 0, stream>>>(emb, W1, b1, W2, b2, Wa1, ba1,
                                              wa2, ba2, H2, L);
  pool_rho<<<V / MT, 256, 0, stream>>>(ids, L, H2, Wr1, br1, Wr2, br2, out);
}

// Round 6
// 217.676 us; speedup vs baseline: 7.5731x; 7.5731x over previous
//
#include <hip/hip_runtime.h>
#include <math.h>

// LearnableVisitEncoder — 3-kernel pipeline, all fp32:
//   A vocab_fused : emb[20000,128] -> H2 = silu(silu(emb@W1+b1)@W2+b2) (stored)
//                   L[r] = tanh(H2@Wa1+ba1) . wa2 + ba2                (stored)
//   B pool_kernel : per visit masked softmax over L[ids], HP = sum a_c H2[id_c]
//   C rho_fused   : out = silu(HP@Wr1+br1)@Wr2 + br2
//
// GEMM: wave-column-split, MT=16 rows/block (vocab 1250 blocks = 4.9/CU,
// rho 1024 = 4.0/CU — fixes round-3's 24% grid-capped occupancy).
// k-loop: `#pragma unroll 4`, static indices ONLY. Round 4 (runtime-indexed
// ping-pong) and round 5 (full unroll) both spilled to scratch (2.6/3.4 GB
// HBM traffic). unroll-4 is the proven-clean configuration (VGPR 52,
// FETCH 5.9 MB in round 3). DO NOT increase unroll or add prefetch arrays.

#define DIM 128
#define MT 16
#define LDP 132   // LDS row stride (528 B), 16B-aligned

__device__ __forceinline__ float silu_f(float v) {
  return v / (1.0f + expf(-v));
}

// stage 16 x 128 fp32 rows (contiguous global) into LDS tile
__device__ __forceinline__ void stage16(const float* __restrict__ src,
                                        float (*dst)[LDP], int tid) {
  const float4* s = (const float4*)src;
#pragma unroll
  for (int t = 0; t < 2; ++t) {
    int idx = tid + t * 256;          // 0..511 float4s = 16 rows x 32
    int r = idx >> 5, c4 = idx & 31;
    *(float4*)&dst[r][c4 * 4] = s[idx];
  }
}

#define FMA2(xs0, xs1, wv)                                                  \
  acc[0][0] = fmaf(xs0, wv.x, acc[0][0]);                                   \
  acc[0][1] = fmaf(xs0, wv.y, acc[0][1]);                                   \
  acc[0][2] = fmaf(xs0, wv.z, acc[0][2]);                                   \
  acc[0][3] = fmaf(xs0, wv.w, acc[0][3]);                                   \
  acc[1][0] = fmaf(xs1, wv.x, acc[1][0]);                                   \
  acc[1][1] = fmaf(xs1, wv.y, acc[1][1]);                                   \
  acc[1][2] = fmaf(xs1, wv.z, acc[1][2]);                                   \
  acc[1][3] = fmaf(xs1, wv.w, acc[1][3]);

// acc[2][4] = sIn[r0..r0+1][:] @ W[:][4*cg..4*cg+3]
// round-3-proven structure: partial unroll 4, static indices
__device__ __forceinline__ void gemm_wave16(const float (*sIn)[LDP],
                                            const float* __restrict__ Wg,
                                            int cg, int r0, float acc[2][4]) {
#pragma unroll
  for (int i = 0; i < 2; ++i)
#pragma unroll
    for (int j = 0; j < 4; ++j) acc[i][j] = 0.f;
  const float4* Wv = (const float4*)Wg;  // W[k][c]: float4 index k*32 + cg
#pragma unroll 4
  for (int k0 = 0; k0 < DIM; k0 += 4) {
    float4 x0 = *(const float4*)&sIn[r0 + 0][k0];
    float4 x1 = *(const float4*)&sIn[r0 + 1][k0];
    float4 w0 = Wv[(k0 + 0) * 32 + cg];
    float4 w1 = Wv[(k0 + 1) * 32 + cg];
    float4 w2 = Wv[(k0 + 2) * 32 + cg];
    float4 w3 = Wv[(k0 + 3) * 32 + cg];
    FMA2(x0.x, x1.x, w0)
    FMA2(x0.y, x1.y, w1)
    FMA2(x0.z, x1.z, w2)
    FMA2(x0.w, x1.w, w3)
  }
}

// ---------------- Kernel A: vocab side, fully fused ----------------
__global__ __launch_bounds__(256, 4) void vocab_fused(
    const float* __restrict__ emb, const float* __restrict__ W1,
    const float* __restrict__ b1, const float* __restrict__ W2,
    const float* __restrict__ b2, const float* __restrict__ Wa1,
    const float* __restrict__ ba1, const float* __restrict__ wa2,
    const float* __restrict__ ba2, float* __restrict__ H2,
    float* __restrict__ L) {
  __shared__ float sA[MT][LDP], sB[MT][LDP];
  __shared__ float sP[4][MT];
  const int tid = threadIdx.x;
  const int wid = tid >> 6, lane = tid & 63;
  const int cg = wid * 8 + (lane & 7);  // float4-col index 0..31
  const int c0 = cg * 4;
  const int r0 = (lane >> 3) * 2;       // 8 row-groups x 2 rows
  const int m0 = blockIdx.x * MT;

  stage16(emb + (size_t)m0 * DIM, sA, tid);
  __syncthreads();

  float acc[2][4];
  // layer 1: silu(emb@W1+b1) -> sB (this wave's 32-col slice)
  gemm_wave16(sA, W1, cg, r0, acc);
  {
    float4 bv = ((const float4*)b1)[cg];
#pragma unroll
    for (int i = 0; i < 2; ++i) {
      float4 o;
      o.x = silu_f(acc[i][0] + bv.x);
      o.y = silu_f(acc[i][1] + bv.y);
      o.z = silu_f(acc[i][2] + bv.z);
      o.w = silu_f(acc[i][3] + bv.w);
      *(float4*)&sB[r0 + i][c0] = o;
    }
  }
  __syncthreads();
  // layer 2: silu(sB@W2+b2) -> sA + global H2
  gemm_wave16(sB, W2, cg, r0, acc);
  {
    float4 bv = ((const float4*)b2)[cg];
#pragma unroll
    for (int i = 0; i < 2; ++i) {
      float4 o;
      o.x = silu_f(acc[i][0] + bv.x);
      o.y = silu_f(acc[i][1] + bv.y);
      o.z = silu_f(acc[i][2] + bv.z);
      o.w = silu_f(acc[i][3] + bv.w);
      *(float4*)&sA[r0 + i][c0] = o;
      *(float4*)&H2[(size_t)(m0 + r0 + i) * DIM + c0] = o;
    }
  }
  __syncthreads();
  // layer 3: tanh(sA@Wa1+ba1) . wa2 + ba2 -> L (rowdot fused)
  gemm_wave16(sA, Wa1, cg, r0, acc);
  {
    float4 bv = ((const float4*)ba1)[cg];
    float4 wv = ((const float4*)wa2)[cg];
#pragma unroll
    for (int i = 0; i < 2; ++i) {
      float g0 = tanhf(acc[i][0] + bv.x);
      float g1 = tanhf(acc[i][1] + bv.y);
      float g2 = tanhf(acc[i][2] + bv.z);
      float g3 = tanhf(acc[i][3] + bv.w);
      float p = fmaf(g0, wv.x, fmaf(g1, wv.y, fmaf(g2, wv.z, g3 * wv.w)));
#pragma unroll
      for (int m = 1; m <= 4; m <<= 1) p += __shfl_xor(p, m, 64);  // 8 cgs
      if ((lane & 7) == 0) sP[wid][r0 + i] = p;
    }
  }
  __syncthreads();
  if (tid < MT)
    L[m0 + tid] = sP[0][tid] + sP[1][tid] + sP[2][tid] + sP[3][tid] + ba2[0];
}

// ---------------- Kernel B: softmax-pool ----------------
// one wave per visit, 4 visits/block; 2 codes per iter via float4/lane
__global__ __launch_bounds__(256, 8) void pool_kernel(
    const int* __restrict__ ids, const float* __restrict__ L,
    const float* __restrict__ H2, float* __restrict__ HP) {
  const int wid = threadIdx.x >> 6, lane = threadIdx.x & 63;
  const int v = blockIdx.x * 4 + wid;

  int id = 0;
  float lg = -3.4e38f;
  if (lane < 48) {
    id = ids[(size_t)v * 48 + lane];
    if (id != 0) lg = L[id];   // PAD_IDX==0 masked
  }
  float mx = lg;
#pragma unroll
  for (int m = 32; m; m >>= 1) mx = fmaxf(mx, __shfl_xor(mx, m, 64));
  float e = (lg > -3.0e38f) ? expf(lg - mx) : 0.f;
  float s = e;
#pragma unroll
  for (int m = 32; m; m >>= 1) s += __shfl_xor(s, m, 64);
  const float a = e / s;           // pads: exactly 0

  const int half = lane >> 5, li = lane & 31;
  float4 acc = make_float4(0.f, 0.f, 0.f, 0.f);
#pragma unroll 8
  for (int c = 0; c < 24; ++c) {   // lanes 0-31: even codes, 32-63: odd
    const int cc = 2 * c + half;
    const float ac = __shfl(a, cc, 64);
    const int idc = __shfl(id, cc, 64);
    const float4 h = ((const float4*)(H2 + (size_t)idc * DIM))[li];
    acc.x = fmaf(ac, h.x, acc.x);  // pad: ac==0 exactly -> no-op
    acc.y = fmaf(ac, h.y, acc.y);
    acc.z = fmaf(ac, h.z, acc.z);
    acc.w = fmaf(ac, h.w, acc.w);
  }
  acc.x += __shfl_xor(acc.x, 32, 64);
  acc.y += __shfl_xor(acc.y, 32, 64);
  acc.z += __shfl_xor(acc.z, 32, 64);
  acc.w += __shfl_xor(acc.w, 32, 64);
  if (half == 0) ((float4*)(HP + (size_t)v * DIM))[li] = acc;
}

// ---------------- Kernel C: rho, fused 2 layers ----------------
__global__ __launch_bounds__(256, 4) void rho_fused(
    const float* __restrict__ HP, const float* __restrict__ Wr1,
    const float* __restrict__ br1, const float* __restrict__ Wr2,
    const float* __restrict__ br2, float* __restrict__ out) {
  __shared__ float sA[MT][LDP], sB[MT][LDP];
  const int tid = threadIdx.x;
  const int wid = tid >> 6, lane = tid & 63;
  const int cg = wid * 8 + (lane & 7);
  const int c0 = cg * 4;
  const int r0 = (lane >> 3) * 2;
  const int m0 = blockIdx.x * MT;

  stage16(HP + (size_t)m0 * DIM, sA, tid);
  __syncthreads();

  float acc[2][4];
  gemm_wave16(sA, Wr1, cg, r0, acc);
  {
    float4 bv = ((const float4*)br1)[cg];
#pragma unroll
    for (int i = 0; i < 2; ++i) {
      float4 o;
      o.x = silu_f(acc[i][0] + bv.x);
      o.y = silu_f(acc[i][1] + bv.y);
      o.z = silu_f(acc[i][2] + bv.z);
      o.w = silu_f(acc[i][3] + bv.w);
      *(float4*)&sB[r0 + i][c0] = o;
    }
  }
  __syncthreads();
  gemm_wave16(sB, Wr2, cg, r0, acc);
  {
    float4 bv = ((const float4*)br2)[cg];
#pragma unroll
    for (int i = 0; i < 2; ++i) {
      float4 o;
      o.x = acc[i][0] + bv.x;
      o.y = acc[i][1] + bv.y;
      o.z = acc[i][2] + bv.z;
      o.w = acc[i][3] + bv.w;
      *(float4*)&out[(size_t)(m0 + r0 + i) * DIM + c0] = o;
    }
  }
}

extern "C" void kernel_launch(void* const* d_in, const int* in_sizes, int n_in,
                              void* d_out, int out_size, void* d_ws,
                              size_t ws_size, hipStream_t stream) {
  const int*   ids = (const int*)  d_in[0];
  const float* emb = (const float*)d_in[1];
  const float* W1  = (const float*)d_in[2];
  const float* b1  = (const float*)d_in[3];
  const float* W2  = (const float*)d_in[4];
  const float* b2  = (const float*)d_in[5];
  const float* Wa1 = (const float*)d_in[6];
  const float* ba1 = (const float*)d_in[7];
  const float* wa2 = (const float*)d_in[8];
  const float* ba2 = (const float*)d_in[9];
  const float* Wr1 = (const float*)d_in[10];
  const float* br1 = (const float*)d_in[11];
  const float* Wr2 = (const float*)d_in[12];
  const float* br2 = (const float*)d_in[13];
  float* out = (float*)d_out;

  const int VOCAB = 20000, V = 16384;

  float* H2 = (float*)d_ws;                       // 20000*128
  float* L  = H2 + (size_t)VOCAB * DIM;           // 20000
  float* HP = L + VOCAB;                          // 16384*128 (16B-aligned)

  vocab_fused<<<VOCAB / MT, 256, 0, stream>>>(emb, W1, b1, W2, b2, Wa1, ba1,
                                              wa2, ba2, H2, L);
  pool_kernel<<<V / 4, 256, 0, stream>>>(ids, L, H2, HP);
  rho_fused<<<V / MT, 256, 0, stream>>>(HP, Wr1, br1, Wr2, br2, out);
}

// Round 7
// 201.070 us; speedup vs baseline: 8.1985x; 1.0826x over previous
//
#include <hip/hip_runtime.h>
#include <math.h>

// LearnableVisitEncoder — 3-kernel pipeline, all fp32:
//   A vocab_fused : emb[20000,128] -> H2 = silu(silu(emb@W1+b1)@W2+b2) (stored)
//                   L[r] = tanh(H2@Wa1+ba1) . wa2 + ba2                (stored)
//   B pool_kernel : per visit masked softmax over L[ids], HP = sum a_c H2[id_c]
//   C rho_fused   : out = silu(HP@Wr1+br1)@Wr2 + br2
//
// GEMM: wave-column-split, MT=32 (r3-proven). k-loop = manual 2-deep
// software pipeline with NAMED float4 scalars only.
// Journal constraints (hard-won):
//   - r4: runtime-indexed local arrays -> scratch spill (2.6 GB HBM). NEVER.
//   - r5: full unroll of the k-loop -> scratch spill (3.4 GB HBM). NEVER.
//   - r6: MT=16 (more blocks, less ILP/wave) regressed: latency exposure per
//     wave is the binding constraint, not occupancy.
//   - unroll-4 plain (r3): VGPR 52, clean, 56 us vocab, VALUBusy 31%.
// This round: same memory footprint as r3, but every load group gets >=128cy
// of independent FMA cover -> predict VALUBusy ~2x.

#define DIM 128
#define MT 32
#define LDP 132   // LDS row stride (528 B), 16B-aligned

__device__ __forceinline__ float silu_f(float v) {
  return v / (1.0f + expf(-v));
}

// stage 32 x 128 fp32 rows (contiguous global) into LDS tile
__device__ __forceinline__ void stage32(const float* __restrict__ src,
                                        float (*dst)[LDP], int tid) {
  const float4* s = (const float4*)src;
#pragma unroll
  for (int t = 0; t < 4; ++t) {
    int idx = tid + t * 256;          // 0..1023 float4s = 32 rows x 32
    int r = idx >> 5, c4 = idx & 31;
    *(float4*)&dst[r][c4 * 4] = s[idx];
  }
}

// 16 FMAs: one k-step, 4 rows x 4 cols
#define FMA16(xx0, xx1, xx2, xx3, wv)                                       \
  acc[0][0] = fmaf(xx0, wv.x, acc[0][0]);                                   \
  acc[0][1] = fmaf(xx0, wv.y, acc[0][1]);                                   \
  acc[0][2] = fmaf(xx0, wv.z, acc[0][2]);                                   \
  acc[0][3] = fmaf(xx0, wv.w, acc[0][3]);                                   \
  acc[1][0] = fmaf(xx1, wv.x, acc[1][0]);                                   \
  acc[1][1] = fmaf(xx1, wv.y, acc[1][1]);                                   \
  acc[1][2] = fmaf(xx1, wv.z, acc[1][2]);                                   \
  acc[1][3] = fmaf(xx1, wv.w, acc[1][3]);                                   \
  acc[2][0] = fmaf(xx2, wv.x, acc[2][0]);                                   \
  acc[2][1] = fmaf(xx2, wv.y, acc[2][1]);                                   \
  acc[2][2] = fmaf(xx2, wv.z, acc[2][2]);                                   \
  acc[2][3] = fmaf(xx2, wv.w, acc[2][3]);                                   \
  acc[3][0] = fmaf(xx3, wv.x, acc[3][0]);                                   \
  acc[3][1] = fmaf(xx3, wv.y, acc[3][1]);                                   \
  acc[3][2] = fmaf(xx3, wv.z, acc[3][2]);                                   \
  acc[3][3] = fmaf(xx3, wv.w, acc[3][3]);

// one 4-k chunk: k ascending (order-preserving vs r3)
#define FMACHUNK(X0, X1, X2, X3, W0, W1, W2, W3)                            \
  FMA16(X0.x, X1.x, X2.x, X3.x, W0)                                         \
  FMA16(X0.y, X1.y, X2.y, X3.y, W1)                                         \
  FMA16(X0.z, X1.z, X2.z, X3.z, W2)                                         \
  FMA16(X0.w, X1.w, X2.w, X3.w, W3)

#define LOADCHUNK(X0, X1, X2, X3, W0, W1, W2, W3, K0)                       \
  X0 = *(const float4*)&sIn[r0 + 0][K0];                                    \
  X1 = *(const float4*)&sIn[r0 + 1][K0];                                    \
  X2 = *(const float4*)&sIn[r0 + 2][K0];                                    \
  X3 = *(const float4*)&sIn[r0 + 3][K0];                                    \
  W0 = Wv[(K0 + 0) * 32 + cg];                                              \
  W1 = Wv[(K0 + 1) * 32 + cg];                                              \
  W2 = Wv[(K0 + 2) * 32 + cg];                                              \
  W3 = Wv[(K0 + 3) * 32 + cg];

// acc[4][4] = sIn[r0..r0+3][:] @ W[:][4*cg..4*cg+3]
// manual 2-deep pipeline, named scalars, unroll 1 (see journal constraints)
__device__ __forceinline__ void gemm_wave(const float (*sIn)[LDP],
                                          const float* __restrict__ Wg,
                                          int cg, int r0, float acc[4][4]) {
#pragma unroll
  for (int i = 0; i < 4; ++i)
#pragma unroll
    for (int j = 0; j < 4; ++j) acc[i][j] = 0.f;
  const float4* Wv = (const float4*)Wg;  // W[k][c]: float4 index k*32 + cg

  float4 xa0, xa1, xa2, xa3, wa0, wa1, wa2, wa3;   // even chunks
  float4 xb0, xb1, xb2, xb3, wb0, wb1, wb2, wb3;   // odd chunks

  LOADCHUNK(xa0, xa1, xa2, xa3, wa0, wa1, wa2, wa3, 0)
#pragma unroll 1
  for (int p = 0; p < 16; ++p) {
    const int kb = p * 8 + 4;
    LOADCHUNK(xb0, xb1, xb2, xb3, wb0, wb1, wb2, wb3, kb)
    FMACHUNK(xa0, xa1, xa2, xa3, wa0, wa1, wa2, wa3)      // chunk 2p
    if (p < 15) {
      const int ka = p * 8 + 8;
      LOADCHUNK(xa0, xa1, xa2, xa3, wa0, wa1, wa2, wa3, ka)
    }
    FMACHUNK(xb0, xb1, xb2, xb3, wb0, wb1, wb2, wb3)      // chunk 2p+1
  }
}

// ---------------- Kernel A: vocab side, fully fused ----------------
__global__ __launch_bounds__(256, 4) void vocab_fused(
    const float* __restrict__ emb, const float* __restrict__ W1,
    const float* __restrict__ b1, const float* __restrict__ W2,
    const float* __restrict__ b2, const float* __restrict__ Wa1,
    const float* __restrict__ ba1, const float* __restrict__ wa2,
    const float* __restrict__ ba2, float* __restrict__ H2,
    float* __restrict__ L) {
  __shared__ float sA[MT][LDP], sB[MT][LDP];
  __shared__ float sP[4][MT];
  const int tid = threadIdx.x;
  const int wid = tid >> 6, lane = tid & 63;
  const int cg = wid * 8 + (lane & 7);  // float4-col index 0..31
  const int c0 = cg * 4;
  const int r0 = (lane >> 3) * 4;       // 8 row-groups x 4 rows
  const int m0 = blockIdx.x * MT;

  stage32(emb + (size_t)m0 * DIM, sA, tid);
  __syncthreads();

  float acc[4][4];
  // layer 1: silu(emb@W1+b1) -> sB (this wave's 32-col slice)
  gemm_wave(sA, W1, cg, r0, acc);
  {
    float4 bv = ((const float4*)b1)[cg];
#pragma unroll
    for (int i = 0; i < 4; ++i) {
      float4 o;
      o.x = silu_f(acc[i][0] + bv.x);
      o.y = silu_f(acc[i][1] + bv.y);
      o.z = silu_f(acc[i][2] + bv.z);
      o.w = silu_f(acc[i][3] + bv.w);
      *(float4*)&sB[r0 + i][c0] = o;
    }
  }
  __syncthreads();
  // layer 2: silu(sB@W2+b2) -> sA + global H2
  gemm_wave(sB, W2, cg, r0, acc);
  {
    float4 bv = ((const float4*)b2)[cg];
#pragma unroll
    for (int i = 0; i < 4; ++i) {
      float4 o;
      o.x = silu_f(acc[i][0] + bv.x);
      o.y = silu_f(acc[i][1] + bv.y);
      o.z = silu_f(acc[i][2] + bv.z);
      o.w = silu_f(acc[i][3] + bv.w);
      *(float4*)&sA[r0 + i][c0] = o;
      *(float4*)&H2[(size_t)(m0 + r0 + i) * DIM + c0] = o;
    }
  }
  __syncthreads();
  // layer 3: tanh(sA@Wa1+ba1) . wa2 + ba2 -> L (rowdot fused)
  gemm_wave(sA, Wa1, cg, r0, acc);
  {
    float4 bv = ((const float4*)ba1)[cg];
    float4 wv = ((const float4*)wa2)[cg];
#pragma unroll
    for (int i = 0; i < 4; ++i) {
      float g0 = tanhf(acc[i][0] + bv.x);
      float g1 = tanhf(acc[i][1] + bv.y);
      float g2 = tanhf(acc[i][2] + bv.z);
      float g3 = tanhf(acc[i][3] + bv.w);
      float p = fmaf(g0, wv.x, fmaf(g1, wv.y, fmaf(g2, wv.z, g3 * wv.w)));
#pragma unroll
      for (int m = 1; m <= 4; m <<= 1) p += __shfl_xor(p, m, 64);  // 8 cgs
      if ((lane & 7) == 0) sP[wid][r0 + i] = p;
    }
  }
  __syncthreads();
  if (tid < MT)
    L[m0 + tid] = sP[0][tid] + sP[1][tid] + sP[2][tid] + sP[3][tid] + ba2[0];
}

// ---------------- Kernel B: softmax-pool ----------------
// one wave per visit, 4 visits/block; 2 codes per iter via float4/lane
__global__ __launch_bounds__(256, 8) void pool_kernel(
    const int* __restrict__ ids, const float* __restrict__ L,
    const float* __restrict__ H2, float* __restrict__ HP) {
  const int wid = threadIdx.x >> 6, lane = threadIdx.x & 63;
  const int v = blockIdx.x * 4 + wid;

  int id = 0;
  float lg = -3.4e38f;
  if (lane < 48) {
    id = ids[(size_t)v * 48 + lane];
    if (id != 0) lg = L[id];   // PAD_IDX==0 masked
  }
  float mx = lg;
#pragma unroll
  for (int m = 32; m; m >>= 1) mx = fmaxf(mx, __shfl_xor(mx, m, 64));
  float e = (lg > -3.0e38f) ? expf(lg - mx) : 0.f;
  float s = e;
#pragma unroll
  for (int m = 32; m; m >>= 1) s += __shfl_xor(s, m, 64);
  const float a = e / s;           // pads: exactly 0

  const int half = lane >> 5, li = lane & 31;
  float4 acc = make_float4(0.f, 0.f, 0.f, 0.f);
#pragma unroll 8
  for (int c = 0; c < 24; ++c) {   // lanes 0-31: even codes, 32-63: odd
    const int cc = 2 * c + half;
    const float ac = __shfl(a, cc, 64);
    const int idc = __shfl(id, cc, 64);
    const float4 h = ((const float4*)(H2 + (size_t)idc * DIM))[li];
    acc.x = fmaf(ac, h.x, acc.x);  // pad: ac==0 exactly -> no-op
    acc.y = fmaf(ac, h.y, acc.y);
    acc.z = fmaf(ac, h.z, acc.z);
    acc.w = fmaf(ac, h.w, acc.w);
  }
  acc.x += __shfl_xor(acc.x, 32, 64);
  acc.y += __shfl_xor(acc.y, 32, 64);
  acc.z += __shfl_xor(acc.z, 32, 64);
  acc.w += __shfl_xor(acc.w, 32, 64);
  if (half == 0) ((float4*)(HP + (size_t)v * DIM))[li] = acc;
}

// ---------------- Kernel C: rho, fused 2 layers ----------------
__global__ __launch_bounds__(256, 4) void rho_fused(
    const float* __restrict__ HP, const float* __restrict__ Wr1,
    const float* __restrict__ br1, const float* __restrict__ Wr2,
    const float* __restrict__ br2, float* __restrict__ out) {
  __shared__ float sA[MT][LDP], sB[MT][LDP];
  const int tid = threadIdx.x;
  const int wid = tid >> 6, lane = tid & 63;
  const int cg = wid * 8 + (lane & 7);
  const int c0 = cg * 4;
  const int r0 = (lane >> 3) * 4;
  const int m0 = blockIdx.x * MT;

  stage32(HP + (size_t)m0 * DIM, sA, tid);
  __syncthreads();

  float acc[4][4];
  gemm_wave(sA, Wr1, cg, r0, acc);
  {
    float4 bv = ((const float4*)br1)[cg];
#pragma unroll
    for (int i = 0; i < 4; ++i) {
      float4 o;
      o.x = silu_f(acc[i][0] + bv.x);
      o.y = silu_f(acc[i][1] + bv.y);
      o.z = silu_f(acc[i][2] + bv.z);
      o.w = silu_f(acc[i][3] + bv.w);
      *(float4*)&sB[r0 + i][c0] = o;
    }
  }
  __syncthreads();
  gemm_wave(sB, Wr2, cg, r0, acc);
  {
    float4 bv = ((const float4*)br2)[cg];
#pragma unroll
    for (int i = 0; i < 4; ++i) {
      float4 o;
      o.x = acc[i][0] + bv.x;
      o.y = acc[i][1] + bv.y;
      o.z = acc[i][2] + bv.z;
      o.w = acc[i][3] + bv.w;
      *(float4*)&out[(size_t)(m0 + r0 + i) * DIM + c0] = o;
    }
  }
}

extern "C" void kernel_launch(void* const* d_in, const int* in_sizes, int n_in,
                              void* d_out, int out_size, void* d_ws,
                              size_t ws_size, hipStream_t stream) {
  const int*   ids = (const int*)  d_in[0];
  const float* emb = (const float*)d_in[1];
  const float* W1  = (const float*)d_in[2];
  const float* b1  = (const float*)d_in[3];
  const float* W2  = (const float*)d_in[4];
  const float* b2  = (const float*)d_in[5];
  const float* Wa1 = (const float*)d_in[6];
  const float* ba1 = (const float*)d_in[7];
  const float* wa2 = (const float*)d_in[8];
  const float* ba2 = (const float*)d_in[9];
  const float* Wr1 = (const float*)d_in[10];
  const float* br1 = (const float*)d_in[11];
  const float* Wr2 = (const float*)d_in[12];
  const float* br2 = (const float*)d_in[13];
  float* out = (float*)d_out;

  const int VOCAB = 20000, V = 16384;

  float* H2 = (float*)d_ws;                       // 20000*128
  float* L  = H2 + (size_t)VOCAB * DIM;           // 20000
  float* HP = L + VOCAB;                          // 16384*128 (16B-aligned)

  vocab_fused<<<VOCAB / MT, 256, 0, stream>>>(emb, W1, b1, W2, b2, Wa1, ba1,
                                              wa2, ba2, H2, L);
  pool_kernel<<<V / 4, 256, 0, stream>>>(ids, L, H2, HP);
  rho_fused<<<V / MT, 256, 0, stream>>>(HP, Wr1, br1, Wr2, br2, out);
}